// Round 4
// baseline (228.538 us; speedup 1.0000x reference)
//
#include <hip/hip_runtime.h>
#include <stdint.h>

// DeformableFusionAcrossFocus — round 10: transpose-free staging, 3 blocks/CU.
// x:(2,64,16,96,96) f32 | w_off:(6,64,3) | b_off:(6) | w_def:(64,64,3) | b_def:(64) -> out f32
// Tile = (b,h,16w): pos = n*16+w in [0,256). Grid 1152 blocks x 512 thr, 1 tile each.
// Staging: thread owns pos = t&255, channels cb..cb+31 (cb=(t>>8)*32); 32 scalar
// dword loads at c-stride. Lanes 0-15 of each load = 16 consecutive w = one full
// aligned 64B line (4 lines/instr, same 1024 line-requests/block as r9's dwordx4
// scheme). Thread data is c-contiguous -> 16 cvt_pk + 4 ds_write_b128 STRAIGHT into
// xs_t[pos][c] — no xstage (-32KB LDS), no transpose phase, ONE barrier per block.
// LDS 43008 -> 3 blocks/CU = 24 waves (r9: 2 blocks/16 waves). Conv/interp/GEMM/
// epilogue byte-identical to r9 (proven). Every out-row write = one full 64B line.

typedef __attribute__((ext_vector_type(8))) short short8;
typedef __attribute__((ext_vector_type(4))) float f32x4;
typedef __attribute__((ext_vector_type(2))) float f32x2;
typedef __attribute__((ext_vector_type(4))) unsigned int u32x4;

// LDS (bytes):
//  [0,36864)      xs_t bf16 [pos][72 shorts] (row stride 144B; 64 c used + 8 pad)
//  [36864,43008)  offs f32 [6][256] (same-wave produce/consume)
#define XT_OFF   0
#define OFFS_OFF 36864
#define LDS_BYTES 43008   // 3 blocks/CU: 3*43008 = 129024 <= 163840

__device__ __forceinline__ short f2bf(float f) {
  union { float f; uint32_t u; } v; v.f = f;
  uint32_t r = (v.u + 0x7FFFu + ((v.u >> 16) & 1u)) >> 16;
  return (short)r;
}
__device__ __forceinline__ float asf(uint32_t u) {
  union { uint32_t u; float f; } v; v.u = u; return v.f;
}
__device__ __forceinline__ uint32_t cvt_pk_bf16(float lo, float hi) {
  uint32_t d;
  asm("v_cvt_pk_bf16_f32 %0, %1, %2" : "=v"(d) : "v"(lo), "v"(hi));
  return d;
}

// ---- prep: pre-swizzle w_def (frags [0,1536)) and w_off (frags [1536,1920)) into ws ----
__global__ __launch_bounds__(256) void prep_kernel(
    const float* __restrict__ w_off, const float* __restrict__ w_def, short8* __restrict__ ws)
{
  int gid = blockIdx.x * 256 + threadIdx.x;
  if (gid < 1536) {                      // q = (mt*6+ks)*64 + lane
    int mt = gid / 384, ks = (gid % 384) >> 6, ll = gid & 63;
    int m = mt * 16 + (ll & 15), rgq = ll >> 4;
    short8 v;
    #pragma unroll
    for (int jj = 0; jj < 8; ++jj) {
      int kk = ks * 32 + rgq * 8 + jj;
      int c = kk & 63, k3 = kk >> 6;
      v[jj] = f2bf(w_def[m * 192 + c * 3 + k3]);
    }
    ws[gid] = v;
  } else if (gid < 1920) {               // q = ks*64 + lane (rows 6..15 zero)
    int q = gid - 1536;
    int ks = q >> 6, ll = q & 63;
    int m = ll & 15, rgq = ll >> 4;
    short8 v;
    #pragma unroll
    for (int jj = 0; jj < 8; ++jj) {
      int kk = ks * 32 + rgq * 8 + jj;
      int c = kk & 63, k3 = kk >> 6;
      v[jj] = (m < 6) ? f2bf(w_off[m * 192 + c * 3 + k3]) : (short)0;
    }
    ws[gid] = v;
  }
}

__global__ __launch_bounds__(512, 6) void deform_main(
    const float* __restrict__ x, const float* __restrict__ b_off,
    const float* __restrict__ b_def, const short8* __restrict__ wfr,
    float* __restrict__ out)
{
  extern __shared__ char smem[];
  float* offs = (float*)(smem + OFFS_OFF);

  const int t = threadIdx.x, wv = t >> 6, l = t & 63, col = l & 15, rg = l >> 4;
  const int tn = blockIdx.x;
  const int wt = tn % 6, bh = tn / 6;
  const int h = bh % 96, b = bh / 96, w0 = wt * 16;
  const float* xb = x + (size_t)b * 9437184 + h * 96 + w0;

  // ---- stage x -> xs_t[pos][c] directly (no xstage, no transpose) ----
  {
    int pos = t & 255, cb = (t >> 8) * 32;
    int n_ = pos >> 4, w_ = pos & 15;
    const float* xp = xb + (size_t)cb * 147456 + n_ * 9216 + w_;
    float vv[32];
    #pragma unroll
    for (int c = 0; c < 32; ++c)
      vv[c] = xp[(size_t)c * 147456];
    uint32_t pk[16];
    #pragma unroll
    for (int q = 0; q < 16; ++q) pk[q] = cvt_pk_bf16(vv[2 * q], vv[2 * q + 1]);
    #pragma unroll
    for (int q = 0; q < 4; ++q) {
      u32x4 wvec = { pk[4 * q], pk[4 * q + 1], pk[4 * q + 2], pk[4 * q + 3] };
      *(u32x4*)(smem + XT_OFF + pos * 144 + cb * 2 + q * 16) = wvec;
    }
  }
  __syncthreads();   // the ONLY barrier: xs_t complete

  // ---- offsets conv via MFMA; offs produced & consumed by the SAME wave ----
  {
    f32x4 cacc[2] = {{0.f,0.f,0.f,0.f},{0.f,0.f,0.f,0.f}};
    const short8 zero = {0,0,0,0,0,0,0,0};
    #pragma unroll
    for (int ks = 0; ks < 6; ++ks) {
      short8 av = wfr[1536 + ks * 64 + l];
      int k3 = ks >> 1;
      #pragma unroll
      for (int nt2 = 0; nt2 < 2; ++nt2) {
        int n = wv * 2 + nt2;              // pos = n*16 + col
        int row = n + k3 - 1;
        bool valid = (row >= 0) && (row < 16);
        int rcl = min(max(row, 0), 15);
        short8 bv = *(short8*)(smem + XT_OFF + (rcl * 16 + col) * 144 + rg * 16 + (ks & 1) * 64);
        bv = valid ? bv : zero;
        cacc[nt2] = __builtin_amdgcn_mfma_f32_16x16x32_bf16(av, bv, cacc[nt2], 0, 0, 0);
      }
    }
    #pragma unroll
    for (int nt2 = 0; nt2 < 2; ++nt2) {
      int pos = (wv * 2 + nt2) * 16 + col;
      #pragma unroll
      for (int r = 0; r < 4; ++r) {
        int rowo = rg * 4 + r;
        if (rowo < 6) offs[rowo * 256 + pos] = cacc[nt2][r];
      }
    }
  }
  // no barrier: same-wave LDS ordering suffices (offs pos ranges are per-wave)

  // ---- interp params, per-lane in registers (all loop indices constant) ----
  float a0v[3][2], a1v[3][2]; int rb[3][2];
  #pragma unroll
  for (int k = 0; k < 3; ++k) {
    #pragma unroll
    for (int nt2 = 0; nt2 < 2; ++nt2) {
      int n = wv * 2 + nt2;
      int pos = n * 16 + col;
      float oy = offs[(2 * k) * 256 + pos] + b_off[2 * k];
      float ox = offs[(2 * k + 1) * 256 + pos] + b_off[2 * k + 1];
      float px = (float)(n - 1 + k) + ox;
      float x0f = floorf(px);
      float fx = px - x0f;
      int x0 = (int)x0f;
      float wy = fmaxf(0.f, 1.f - fabsf(oy));
      float wt1v = fx * wy;
      float wt0v = wy - wt1v;
      float a0, a1; int r0;
      if (x0 >= 0 && x0 < 15)  { r0 = x0; a0 = wt0v; a1 = wt1v; }
      else if (x0 == 15)       { r0 = 14; a0 = 0.f;  a1 = wt0v; }  // only row 15 (=x0)
      else if (x0 == -1)       { r0 = 0;  a0 = wt1v; a1 = 0.f;  }  // only row 0 (=x1)
      else                     { r0 = 0;  a0 = 0.f;  a1 = 0.f;  }
      a0v[k][nt2] = a0; a1v[k][nt2] = a1;
      rb[k][nt2] = (r0 * 16 + col) * 144;
    }
  }

  // ---- main GEMM: 64 o x 32 pos per wave, K=192; fully unrolled ----
  f32x4 acc[4][2];
  #pragma unroll
  for (int mt = 0; mt < 4; ++mt) {
    float4 bd = *(const float4*)(b_def + mt * 16 + rg * 4);
    #pragma unroll
    for (int nt2 = 0; nt2 < 2; ++nt2) {
      acc[mt][nt2][0] = bd.x; acc[mt][nt2][1] = bd.y;
      acc[mt][nt2][2] = bd.z; acc[mt][nt2][3] = bd.w;
    }
  }
  #pragma unroll
  for (int k3 = 0; k3 < 3; ++k3) {
    #pragma unroll
    for (int ks2 = 0; ks2 < 2; ++ks2) {
      int ks = k3 * 2 + ks2;
      short8 A[4];
      #pragma unroll
      for (int mt = 0; mt < 4; ++mt) A[mt] = wfr[(mt * 6 + ks) * 64 + l];
      #pragma unroll
      for (int nt2 = 0; nt2 < 2; ++nt2) {
        const char* base = smem + XT_OFF + rb[k3][nt2] + rg * 16 + ks2 * 64;
        u32x4 x0 = *(const u32x4*)base;
        u32x4 x1 = *(const u32x4*)(base + 2304);   // tap row r0+1 (16 pos x stride 144)
        f32x2 A0 = {a0v[k3][nt2], a0v[k3][nt2]};
        f32x2 A1 = {a1v[k3][nt2], a1v[k3][nt2]};
        union { uint32_t w[4]; short8 s; } bu;
        #pragma unroll
        for (int q = 0; q < 4; ++q) {
          uint32_t u0 = x0[q], u1 = x1[q];
          f32x2 X0 = { asf(u0 << 16), asf(u0 & 0xffff0000u) };
          f32x2 X1 = { asf(u1 << 16), asf(u1 & 0xffff0000u) };
          f32x2 R = A0 * X0 + A1 * X1;
          bu.w[q] = cvt_pk_bf16(R.x, R.y);
        }
        short8 bv = bu.s;
        #pragma unroll
        for (int mt = 0; mt < 4; ++mt)
          acc[mt][nt2] = __builtin_amdgcn_mfma_f32_16x16x32_bf16(A[mt], bv, acc[mt][nt2], 0, 0, 0);
      }
    }
  }

  // ---- epilogue: direct stores; each 16-lane group writes one full 64B line ----
  float* ob = out + (size_t)b * 9437184 + h * 96 + w0;
  #pragma unroll
  for (int mt = 0; mt < 4; ++mt) {
    #pragma unroll
    for (int nt2 = 0; nt2 < 2; ++nt2) {
      int n = wv * 2 + nt2;
      float* o0 = ob + (size_t)((mt * 16 + rg * 4) * 16 + n) * 9216 + col;
      #pragma unroll
      for (int r = 0; r < 4; ++r)
        o0[(size_t)r * 147456] = acc[mt][nt2][r];   // o stride = 16*9216
    }
  }
}

extern "C" void kernel_launch(void* const* d_in, const int* in_sizes, int n_in,
                              void* d_out, int out_size, void* d_ws, size_t ws_size,
                              hipStream_t stream) {
  (void)in_sizes; (void)n_in; (void)ws_size; (void)out_size;
  const float* x     = (const float*)d_in[0];
  const float* w_off = (const float*)d_in[1];
  const float* b_off = (const float*)d_in[2];
  const float* w_def = (const float*)d_in[3];
  const float* b_def = (const float*)d_in[4];
  float* out = (float*)d_out;
  short8* wfr = (short8*)d_ws;   // 1920 * 16B = 30720 B of scratch

  (void)hipFuncSetAttribute((const void*)deform_main,
                            hipFuncAttributeMaxDynamicSharedMemorySize, LDS_BYTES);
  prep_kernel<<<dim3(8), dim3(256), 0, stream>>>(w_off, w_def, wfr);
  deform_main<<<dim3(1152), dim3(512), LDS_BYTES, stream>>>(x, b_off, b_def, wfr, out);
}